// Round 8
// baseline (69.343 us; speedup 1.0000x reference)
//
#include <hip/hip_runtime.h>

// Propagation2: out[b, k, y, x] = in[b, 0, clamp(y+dy_k), clamp(x+dx_k)]
// (one-hot 5x5 conv filters == shifted copies with replication pad 2).
//
// Winning structure (R4/R6): thread owns all 9 planes; XCD-chunked swizzle
// keeps each batch's 2.09 MB input L2-resident (40.3 -> 29.6 us); NT stores
// beat cached (29.57 vs 30.46). Plane-split (R7) regressed (42 us).
//
// R8: 8 floats/thread (two f4 quads). Each wave now writes 2 KB contiguous
// per plane (2 back-to-back NT dwordx4) instead of 1 KB -> longer DRAM
// bursts per stream, half the address setup, same total traffic.

#define H_DIM 544
#define W_DIM 960

typedef float f4 __attribute__((ext_vector_type(4)));

__global__ __launch_bounds__(256) void Propagation2_kernel(
    const float* __restrict__ in, float* __restrict__ out, int B, int H, int W,
    int chunks_per_xcd)
{
    // chunked XCD swizzle (bijective: grid % 8 == 0, guaranteed by launcher)
    int bid = blockIdx.x;
    int swz = (bid & 7) * chunks_per_xcd + (bid >> 3);
    int idx = swz * blockDim.x + threadIdx.x;

    const int opr = W >> 3;              // octs (8 floats) per row = 120
    int total = B * H * opr;
    if (idx >= total) return;

    int q    = idx % opr;
    int rest = idx / opr;
    int y    = rest % H;
    int b    = rest / H;
    int x0   = q << 3;                   // 0..952, 8-aligned

    const float* base = in + (size_t)b * H * W;
    int ym2 = (y - 2 < 0) ? 0 : y - 2;
    int ym1 = (y - 1 < 0) ? 0 : y - 1;
    int yp1 = (y + 1 >= H) ? H - 1 : y + 1;
    int yp2 = (y + 2 >= H) ? H - 1 : y + 2;

    const float* r0  = base + (size_t)y   * W;
    const float* rm2 = base + (size_t)ym2 * W;
    const float* rm1 = base + (size_t)ym1 * W;
    const float* rp1 = base + (size_t)yp1 * W;
    const float* rp2 = base + (size_t)yp2 * W;

    // clamped scalar x-neighbors (branchless replication padding)
    int xm2 = (x0 - 2 < 0) ? 0 : x0 - 2;
    int xm1 = (x0 - 1 < 0) ? 0 : x0 - 1;
    int xp8 = (x0 + 8 >= W) ? W - 1 : x0 + 8;
    int xp9 = (x0 + 9 >= W) ? W - 1 : x0 + 9;

    // aligned vector loads, two quads per row (always in-bounds)
    f4 c0a  = *(const f4*)(r0  + x0), c0b  = *(const f4*)(r0  + x0 + 4);
    f4 cm2a = *(const f4*)(rm2 + x0), cm2b = *(const f4*)(rm2 + x0 + 4);
    f4 cm1a = *(const f4*)(rm1 + x0), cm1b = *(const f4*)(rm1 + x0 + 4);
    f4 cp1a = *(const f4*)(rp1 + x0), cp1b = *(const f4*)(rp1 + x0 + 4);
    f4 cp2a = *(const f4*)(rp2 + x0), cp2b = *(const f4*)(rp2 + x0 + 4);

    float r0_m2  = r0[xm2],  r0_m1  = r0[xm1];
    float r0_p8  = r0[xp8],  r0_p9  = r0[xp9];
    float rm1_m1 = rm1[xm1], rm1_p8 = rm1[xp8];
    float rp1_m1 = rp1[xm1], rp1_p8 = rp1[xp8];

    size_t HW = (size_t)H * W;
    float* ob = out + (size_t)b * 9 * HW + (size_t)y * W + x0;

    // OFFSETS = [(-2,0),(0,-2),(0,0),(0,2),(2,0),(-1,-1),(1,1),(-1,1),(1,-1)]
    // plane 0: (-2, 0)
    f4 p0a = cm2a;
    f4 p0b = cm2b;
    // plane 1: (0,-2) -> floats [x0-2 .. x0+5]
    f4 p1a = {r0_m2, r0_m1, c0a.x, c0a.y};
    f4 p1b = {c0a.z, c0a.w, c0b.x, c0b.y};
    // plane 2: (0, 0)
    f4 p2a = c0a;
    f4 p2b = c0b;
    // plane 3: (0, 2) -> [x0+2 .. x0+9]
    f4 p3a = {c0a.z, c0a.w, c0b.x, c0b.y};
    f4 p3b = {c0b.z, c0b.w, r0_p8, r0_p9};
    // plane 4: (2, 0)
    f4 p4a = cp2a;
    f4 p4b = cp2b;
    // plane 5: (-1,-1) -> row ym1, [x0-1 .. x0+6]
    f4 p5a = {rm1_m1, cm1a.x, cm1a.y, cm1a.z};
    f4 p5b = {cm1a.w, cm1b.x, cm1b.y, cm1b.z};
    // plane 6: (1, 1) -> row yp1, [x0+1 .. x0+8]
    f4 p6a = {cp1a.y, cp1a.z, cp1a.w, cp1b.x};
    f4 p6b = {cp1b.y, cp1b.z, cp1b.w, rp1_p8};
    // plane 7: (-1, 1) -> row ym1, [x0+1 .. x0+8]
    f4 p7a = {cm1a.y, cm1a.z, cm1a.w, cm1b.x};
    f4 p7b = {cm1b.y, cm1b.z, cm1b.w, rm1_p8};
    // plane 8: (1,-1) -> row yp1, [x0-1 .. x0+6]
    f4 p8a = {rp1_m1, cp1a.x, cp1a.y, cp1a.z};
    f4 p8b = {cp1a.w, cp1b.x, cp1b.y, cp1b.z};

    __builtin_nontemporal_store(p0a, (f4*)(ob + 0 * HW));
    __builtin_nontemporal_store(p0b, (f4*)(ob + 0 * HW + 4));
    __builtin_nontemporal_store(p1a, (f4*)(ob + 1 * HW));
    __builtin_nontemporal_store(p1b, (f4*)(ob + 1 * HW + 4));
    __builtin_nontemporal_store(p2a, (f4*)(ob + 2 * HW));
    __builtin_nontemporal_store(p2b, (f4*)(ob + 2 * HW + 4));
    __builtin_nontemporal_store(p3a, (f4*)(ob + 3 * HW));
    __builtin_nontemporal_store(p3b, (f4*)(ob + 3 * HW + 4));
    __builtin_nontemporal_store(p4a, (f4*)(ob + 4 * HW));
    __builtin_nontemporal_store(p4b, (f4*)(ob + 4 * HW + 4));
    __builtin_nontemporal_store(p5a, (f4*)(ob + 5 * HW));
    __builtin_nontemporal_store(p5b, (f4*)(ob + 5 * HW + 4));
    __builtin_nontemporal_store(p6a, (f4*)(ob + 6 * HW));
    __builtin_nontemporal_store(p6b, (f4*)(ob + 6 * HW + 4));
    __builtin_nontemporal_store(p7a, (f4*)(ob + 7 * HW));
    __builtin_nontemporal_store(p7b, (f4*)(ob + 7 * HW + 4));
    __builtin_nontemporal_store(p8a, (f4*)(ob + 8 * HW));
    __builtin_nontemporal_store(p8b, (f4*)(ob + 8 * HW + 4));
}

extern "C" void kernel_launch(void* const* d_in, const int* in_sizes, int n_in,
                              void* d_out, int out_size, void* d_ws, size_t ws_size,
                              hipStream_t stream) {
    const float* in = (const float*)d_in[0];
    float* out = (float*)d_out;
    const int H = H_DIM, W = W_DIM;
    int B = in_sizes[0] / (H * W);
    int total = B * H * (W >> 3);
    const int block = 256;
    int grid = (total + block - 1) / block;           // 2040 for B=8 (divisible by 8)
    int chunks_per_xcd = grid / 8;
    Propagation2_kernel<<<grid, block, 0, stream>>>(in, out, B, H, W, chunks_per_xcd);
}

// Round 9
// 30.388 us; speedup vs baseline: 2.2819x; 2.2819x over previous
//
#include <hip/hip_runtime.h>

// Propagation2: out[b, k, y, x] = in[b, 0, clamp(y+dy_k), clamp(x+dx_k)]
// (one-hot 5x5 conv filters == shifted copies with replication pad 2).
//
// Winning structure (R4/R6, 29.44 us): thread owns all 9 planes at one quad;
// XCD-chunked swizzle keeps each batch's 2.09 MB input L2-resident; NT stores.
// R8 lesson: per-store-instruction wave contiguity is mandatory for NT stores
// (8-float/thread put lanes at 32B stride -> partial-segment RMW, 2.35x slower).
//
// R9: vertical pairing — 2 output ROWS x 4 cols per thread. Lanes stay
// x-consecutive per store (packed 1KB/wave) while 6 row-loads serve 2 output
// rows (vs 10), scalar edges 16->12, address setup halved, 18 stores of ILP.

#define H_DIM 544
#define W_DIM 960

typedef float f4 __attribute__((ext_vector_type(4)));

__global__ __launch_bounds__(256) void Propagation2_kernel(
    const float* __restrict__ in, float* __restrict__ out, int B, int H, int W,
    int chunks_per_xcd)
{
    // chunked XCD swizzle (bijective: grid % 8 == 0, guaranteed by launcher)
    int bid = blockIdx.x;
    int swz = (bid & 7) * chunks_per_xcd + (bid >> 3);
    int idx = swz * blockDim.x + threadIdx.x;

    const int qpr = W >> 2;              // 240 quads per row
    const int hp  = H >> 1;              // 272 row-pairs
    int total = B * hp * qpr;
    if (idx >= total) return;

    int q    = idx % qpr;
    int rest = idx / qpr;
    int yp   = rest % hp;
    int b    = rest / hp;
    int x0   = q << 2;
    int y0   = yp << 1;                  // even row
    int y1   = y0 + 1;                   // odd row

    const float* base = in + (size_t)b * H * W;
    // 6 source rows: a=y0-2, b=y0-1, c=y0, d=y1, e=y1+1, f=y1+2 (clamped)
    int ya = (y0 - 2 < 0) ? 0 : y0 - 2;
    int yb = (y0 - 1 < 0) ? 0 : y0 - 1;
    int ye = (y1 + 1 >= H) ? H - 1 : y1 + 1;
    int yf = (y1 + 2 >= H) ? H - 1 : y1 + 2;

    const float* rA = base + (size_t)ya * W;
    const float* rB = base + (size_t)yb * W;
    const float* rC = base + (size_t)y0 * W;
    const float* rD = base + (size_t)y1 * W;
    const float* rE = base + (size_t)ye * W;
    const float* rF = base + (size_t)yf * W;

    // clamped scalar x-neighbors
    int xm2 = (x0 - 2 < 0) ? 0 : x0 - 2;
    int xm1 = (x0 - 1 < 0) ? 0 : x0 - 1;
    int xp4 = (x0 + 4 >= W) ? W - 1 : x0 + 4;
    int xp5 = (x0 + 5 >= W) ? W - 1 : x0 + 5;

    // center quads (aligned, in-bounds)
    f4 A = *(const f4*)(rA + x0);
    f4 Bv = *(const f4*)(rB + x0);
    f4 C = *(const f4*)(rC + x0);
    f4 D = *(const f4*)(rD + x0);
    f4 E = *(const f4*)(rE + x0);
    f4 F = *(const f4*)(rF + x0);

    float b_m1 = rB[xm1], b_p4 = rB[xp4];
    float c_m2 = rC[xm2], c_m1 = rC[xm1], c_p4 = rC[xp4], c_p5 = rC[xp5];
    float d_m2 = rD[xm2], d_m1 = rD[xm1], d_p4 = rD[xp4], d_p5 = rD[xp5];
    float e_m1 = rE[xm1], e_p4 = rE[xp4];

    size_t HW = (size_t)H * W;
    float* ob0 = out + (size_t)b * 9 * HW + (size_t)y0 * W + x0;
    float* ob1 = ob0 + W;

    // OFFSETS = [(-2,0),(0,-2),(0,0),(0,2),(2,0),(-1,-1),(1,1),(-1,1),(1,-1)]
    // row y0: rm2=A, rm1=B, r0=C, rp1=D, rp2=E
    f4 v0 = A;
    f4 v1 = {c_m2, c_m1, C.x, C.y};
    f4 v2 = C;
    f4 v3 = {C.z, C.w, c_p4, c_p5};
    f4 v4 = E;
    f4 v5 = {b_m1, Bv.x, Bv.y, Bv.z};
    f4 v6 = {D.y, D.z, D.w, d_p4};
    f4 v7 = {Bv.y, Bv.z, Bv.w, b_p4};
    f4 v8 = {d_m1, D.x, D.y, D.z};
    // row y1: rm2=B, rm1=C, r0=D, rp1=E, rp2=F
    f4 w0 = Bv;
    f4 w1 = {d_m2, d_m1, D.x, D.y};
    f4 w2 = D;
    f4 w3 = {D.z, D.w, d_p4, d_p5};
    f4 w4 = F;
    f4 w5 = {c_m1, C.x, C.y, C.z};
    f4 w6 = {E.y, E.z, E.w, e_p4};
    f4 w7 = {C.y, C.z, C.w, c_p4};
    f4 w8 = {e_m1, E.x, E.y, E.z};

    __builtin_nontemporal_store(v0, (f4*)(ob0 + 0 * HW));
    __builtin_nontemporal_store(w0, (f4*)(ob1 + 0 * HW));
    __builtin_nontemporal_store(v1, (f4*)(ob0 + 1 * HW));
    __builtin_nontemporal_store(w1, (f4*)(ob1 + 1 * HW));
    __builtin_nontemporal_store(v2, (f4*)(ob0 + 2 * HW));
    __builtin_nontemporal_store(w2, (f4*)(ob1 + 2 * HW));
    __builtin_nontemporal_store(v3, (f4*)(ob0 + 3 * HW));
    __builtin_nontemporal_store(w3, (f4*)(ob1 + 3 * HW));
    __builtin_nontemporal_store(v4, (f4*)(ob0 + 4 * HW));
    __builtin_nontemporal_store(w4, (f4*)(ob1 + 4 * HW));
    __builtin_nontemporal_store(v5, (f4*)(ob0 + 5 * HW));
    __builtin_nontemporal_store(w5, (f4*)(ob1 + 5 * HW));
    __builtin_nontemporal_store(v6, (f4*)(ob0 + 6 * HW));
    __builtin_nontemporal_store(w6, (f4*)(ob1 + 6 * HW));
    __builtin_nontemporal_store(v7, (f4*)(ob0 + 7 * HW));
    __builtin_nontemporal_store(w7, (f4*)(ob1 + 7 * HW));
    __builtin_nontemporal_store(v8, (f4*)(ob0 + 8 * HW));
    __builtin_nontemporal_store(w8, (f4*)(ob1 + 8 * HW));
}

extern "C" void kernel_launch(void* const* d_in, const int* in_sizes, int n_in,
                              void* d_out, int out_size, void* d_ws, size_t ws_size,
                              hipStream_t stream) {
    const float* in = (const float*)d_in[0];
    float* out = (float*)d_out;
    const int H = H_DIM, W = W_DIM;
    int B = in_sizes[0] / (H * W);
    int total = B * (H >> 1) * (W >> 2);
    const int block = 256;
    int grid = (total + block - 1) / block;           // 2040 for B=8 (divisible by 8)
    int chunks_per_xcd = grid / 8;
    Propagation2_kernel<<<grid, block, 0, stream>>>(in, out, B, H, W, chunks_per_xcd);
}

// Round 10
// 29.595 us; speedup vs baseline: 2.3431x; 1.0268x over previous
//
#include <hip/hip_runtime.h>

// Propagation2: out[b, k, y, x] = in[b, 0, clamp(y+dy_k), clamp(x+dx_k)]
// for the 9 offsets of the one-hot 5x5 filters (ReplicationPad2d(2) == clamp).
// Memory-bound: ~16.7 MB read, ~150.4 MB write. FINAL (R4/R6 config, 29.44 us
// = ~5.7 TB/s effective, 90% of measured 6.29 TB/s D2D ceiling).
//
// A/B ledger:
//  - XCD-chunked swizzle (each XCD owns one batch; 2.09 MB input L2-resident):
//    40.3 -> 29.6 us (+27%). The 5x vertical row reuse was crossing XCDs.
//  - NT stores vs cached: 29.57 vs 30.46 -> NT wins (write stream bypasses L2).
//  - Plane-split (1 contiguous stream/block): 42.1 us (9x L2 re-reads, scalar gathers).
//  - 8 floats/thread: 69.3 us (lanes at 32B stride per NT store -> partial-segment RMW;
//    per-store-instruction wave contiguity is mandatory).
//  - 2 rows x 4 cols/thread: 30.4 us (instruction overhead was never the limiter;
//    VALUBusy ~5% throughout).

#define H_DIM 544
#define W_DIM 960

typedef float f4 __attribute__((ext_vector_type(4)));

__global__ __launch_bounds__(256) void Propagation2_kernel(
    const float* __restrict__ in, float* __restrict__ out, int B, int H, int W,
    int chunks_per_xcd)
{
    // chunked XCD swizzle (bijective: grid % 8 == 0, guaranteed by launcher)
    int bid = blockIdx.x;
    int swz = (bid & 7) * chunks_per_xcd + (bid >> 3);
    int idx = swz * blockDim.x + threadIdx.x;

    const int qpr = W >> 2;              // quads per row
    int total = B * H * qpr;
    if (idx >= total) return;

    int q    = idx % qpr;
    int rest = idx / qpr;
    int y    = rest % H;
    int b    = rest / H;
    int x0   = q << 2;

    const float* base = in + (size_t)b * H * W;
    int ym2 = (y - 2 < 0) ? 0 : y - 2;
    int ym1 = (y - 1 < 0) ? 0 : y - 1;
    int yp1 = (y + 1 >= H) ? H - 1 : y + 1;
    int yp2 = (y + 2 >= H) ? H - 1 : y + 2;

    const float* r0  = base + (size_t)y   * W;
    const float* rm2 = base + (size_t)ym2 * W;
    const float* rm1 = base + (size_t)ym1 * W;
    const float* rp1 = base + (size_t)yp1 * W;
    const float* rp2 = base + (size_t)yp2 * W;

    // clamped scalar x-neighbors (branchless replication padding)
    int xm2 = (x0 - 2 < 0) ? 0 : x0 - 2;
    int xm1 = (x0 - 1 < 0) ? 0 : x0 - 1;
    int xp4 = (x0 + 4 >= W) ? W - 1 : x0 + 4;
    int xp5 = (x0 + 5 >= W) ? W - 1 : x0 + 5;

    // aligned vector center loads (always in-bounds: x0 in [0, W-4], x0 % 4 == 0)
    f4 c0  = *(const f4*)(r0  + x0);
    f4 cm2 = *(const f4*)(rm2 + x0);
    f4 cm1 = *(const f4*)(rm1 + x0);
    f4 cp1 = *(const f4*)(rp1 + x0);
    f4 cp2 = *(const f4*)(rp2 + x0);

    float r0_m2  = r0[xm2],  r0_m1  = r0[xm1],  r0_p4  = r0[xp4],  r0_p5 = r0[xp5];
    float rm1_m1 = rm1[xm1], rm1_p4 = rm1[xp4];
    float rp1_m1 = rp1[xm1], rp1_p4 = rp1[xp4];

    size_t HW = (size_t)H * W;
    float* ob = out + (size_t)b * 9 * HW + (size_t)y * W + x0;

    // OFFSETS = [(-2,0),(0,-2),(0,0),(0,2),(2,0),(-1,-1),(1,1),(-1,1),(1,-1)]
    f4 v0 = cm2;                                  // (-2, 0)
    f4 v1 = {r0_m2, r0_m1, c0.x, c0.y};           // ( 0,-2)
    f4 v2 = c0;                                   // ( 0, 0)
    f4 v3 = {c0.z, c0.w, r0_p4, r0_p5};           // ( 0, 2)
    f4 v4 = cp2;                                  // ( 2, 0)
    f4 v5 = {rm1_m1, cm1.x, cm1.y, cm1.z};        // (-1,-1)
    f4 v6 = {cp1.y, cp1.z, cp1.w, rp1_p4};        // ( 1, 1)
    f4 v7 = {cm1.y, cm1.z, cm1.w, rm1_p4};        // (-1, 1)
    f4 v8 = {rp1_m1, cp1.x, cp1.y, cp1.z};        // ( 1,-1)

    __builtin_nontemporal_store(v0, (f4*)(ob + 0 * HW));
    __builtin_nontemporal_store(v1, (f4*)(ob + 1 * HW));
    __builtin_nontemporal_store(v2, (f4*)(ob + 2 * HW));
    __builtin_nontemporal_store(v3, (f4*)(ob + 3 * HW));
    __builtin_nontemporal_store(v4, (f4*)(ob + 4 * HW));
    __builtin_nontemporal_store(v5, (f4*)(ob + 5 * HW));
    __builtin_nontemporal_store(v6, (f4*)(ob + 6 * HW));
    __builtin_nontemporal_store(v7, (f4*)(ob + 7 * HW));
    __builtin_nontemporal_store(v8, (f4*)(ob + 8 * HW));
}

extern "C" void kernel_launch(void* const* d_in, const int* in_sizes, int n_in,
                              void* d_out, int out_size, void* d_ws, size_t ws_size,
                              hipStream_t stream) {
    const float* in = (const float*)d_in[0];
    float* out = (float*)d_out;
    const int H = H_DIM, W = W_DIM;
    int B = in_sizes[0] / (H * W);
    int total = B * H * (W >> 2);
    const int block = 256;
    int grid = (total + block - 1) / block;           // 4080 for B=8 (divisible by 8)
    int chunks_per_xcd = grid / 8;
    Propagation2_kernel<<<grid, block, 0, stream>>>(in, out, B, H, W, chunks_per_xcd);
}